// Round 10
// baseline (159.297 us; speedup 1.0000x reference)
//
#include <hip/hip_runtime.h>
#include <math.h>

#define T_ 30
#define C_ 512
#define N_ 784      // 28*28; 13 n64-tiles (last padded to 832)
#define NW_ 832     // padded n extent (13*64)
#define NA_ 832     // aT n-pitch
#define EPSV 1e-12f

typedef __attribute__((ext_vector_type(8))) short bf16x8;
typedef __attribute__((ext_vector_type(4))) float f32x4;
typedef __attribute__((ext_vector_type(4))) int i32x4;

__device__ __forceinline__ unsigned short f2bf(float f) {
    union { float f; unsigned int u; } v; v.f = f;
    unsigned int r = (v.u + 0x7FFFu + ((v.u >> 16) & 1u)) >> 16;  // RNE
    return (unsigned short)r;
}
__device__ __forceinline__ float bf2f(unsigned short h) {
    union { unsigned int u; float f; } v; v.u = ((unsigned int)h) << 16;
    return v.f;
}

// wh/wl: split-precision bf16 of w, layout [k][c]
__global__ void k_prep(const float* __restrict__ w, unsigned short* __restrict__ wh,
                       unsigned short* __restrict__ wl) {
    int idx = blockIdx.x * 256 + threadIdx.x;  // 0..32767
    float v = w[idx];
    unsigned short h = f2bf(v);
    wh[idx] = h;
    wl[idx] = f2bf(v - bf2f(h));
}

// Partial logits: grid (13 nt64, 2 c-half, 30 t), 256 thr. Block: 64 n x 64 k over
// 256 c (2 passes of 128). Stages x (coalesced 256B rows) into LDS packed
// (bf16hi|bf16lo), 3-product MFMA, writes dense [64n][64k] fp32 tile into
// logitsH/logitsL. Also sumsq atomics.
__global__ __launch_bounds__(256) void k_logits(
    const float* __restrict__ x, const unsigned short* __restrict__ wh,
    const unsigned short* __restrict__ wl, float* __restrict__ logitsH,
    float* __restrict__ logitsL, float* __restrict__ sumsq)
{
    __shared__ __align__(16) char smem[64 * 129 * 4];   // 33024 B
    unsigned int* stage = (unsigned int*)smem;           // [n:64][c:129 pitch]
    float* red = (float*)smem;                           // reuse: [n:64][k:68 pitch]

    int nt = blockIdx.x, ch = blockIdx.y, t = blockIdx.z;
    int n0 = nt * 64;
    int tid = threadIdx.x;
    int w = tid >> 6, L = tid & 63, lid = L & 15, quad = L >> 4;

    int clb = tid >> 4;           // 0..15
    int nseg = (tid & 15) * 4;    // 0..60
    bool vld = (n0 + nseg) < N_;  // 784 % 4 == 0, full float4 or nothing
    float ss[4] = {0.f, 0.f, 0.f, 0.f};

    f32x4 acc[4];
    #pragma unroll
    for (int mt = 0; mt < 4; ++mt)
        #pragma unroll
        for (int r = 0; r < 4; ++r) acc[mt][r] = 0.f;

    #pragma unroll
    for (int cc = 0; cc < 2; ++cc) {
        int cbase = ch * 256 + cc * 128;
        // ---- stage 128 c x 64 n
        #pragma unroll
        for (int p = 0; p < 8; ++p) {
            int cl = p * 16 + clb;
            float4 q = make_float4(0.f, 0.f, 0.f, 0.f);
            if (vld)
                q = *reinterpret_cast<const float4*>(
                    x + ((size_t)(t * C_ + cbase + cl)) * N_ + n0 + nseg);
            float vv[4] = {q.x, q.y, q.z, q.w};
            #pragma unroll
            for (int j = 0; j < 4; ++j) {
                float v = vv[j];
                ss[j] = fmaf(v, v, ss[j]);
                union { float f; unsigned int u; } cvt; cvt.f = v;
                unsigned int hiw = cvt.u & 0xFFFF0000u;        // truncated bf16 hi
                union { unsigned int u; float f; } hv; hv.u = hiw;
                unsigned int lo = f2bf(v - hv.f);              // RNE residual
                stage[(nseg + j) * 129 + cl] = hiw | lo;
            }
        }
        __syncthreads();
        // ---- MFMA: wave w owns n-rows w*16..+15, this pass's 128 c (4 ksteps)
        #pragma unroll
        for (int ks = 0; ks < 4; ++ks) {
            int cl0 = ks * 32 + quad * 8;
            unsigned int u[8];
            #pragma unroll
            for (int e = 0; e < 8; ++e)
                u[e] = stage[(w * 16 + lid) * 129 + cl0 + e];
            union { i32x4 v; bf16x8 b; } bh, bl;
            #pragma unroll
            for (int e2 = 0; e2 < 4; ++e2) {
                bh.v[e2] = (int)((u[2 * e2] >> 16) | (u[2 * e2 + 1] & 0xFFFF0000u));
                bl.v[e2] = (int)((u[2 * e2] & 0xFFFFu) | (u[2 * e2 + 1] << 16));
            }
            int cs = cbase + ks * 32 + quad * 8;
            #pragma unroll
            for (int mt = 0; mt < 4; ++mt) {
                bf16x8 ah = *reinterpret_cast<const bf16x8*>(wh + (size_t)(mt * 16 + lid) * C_ + cs);
                bf16x8 al = *reinterpret_cast<const bf16x8*>(wl + (size_t)(mt * 16 + lid) * C_ + cs);
                acc[mt] = __builtin_amdgcn_mfma_f32_16x16x32_bf16(ah, bh.b, acc[mt], 0, 0, 0);
                acc[mt] = __builtin_amdgcn_mfma_f32_16x16x32_bf16(al, bh.b, acc[mt], 0, 0, 0);
                acc[mt] = __builtin_amdgcn_mfma_f32_16x16x32_bf16(ah, bl.b, acc[mt], 0, 0, 0);
            }
        }
        __syncthreads();
    }

    // sumsq partial (256 c of this block): reduce over c-rows within wave, then atomic
    #pragma unroll
    for (int j = 0; j < 4; ++j) {
        ss[j] += __shfl_xor(ss[j], 16, 64);
        ss[j] += __shfl_xor(ss[j], 32, 64);
    }
    if (L < 16 && vld) {
        #pragma unroll
        for (int j = 0; j < 4; ++j)
            atomicAdd(&sumsq[t * N_ + n0 + L * 4 + j], ss[j]);
    }

    // stage dead -> reuse as red
    {
        float* rp = red + (w * 16 + lid) * 68;
        #pragma unroll
        for (int mt = 0; mt < 4; ++mt)
            *reinterpret_cast<f32x4*>(&rp[mt * 16 + quad * 4]) = acc[mt];
    }
    __syncthreads();

    // coalesced dense store: thread -> n = tid>>2, kseg = tid&3
    float* dst = (ch == 0 ? logitsH : logitsL);
    int n = tid >> 2, kseg = (tid & 3) * 16;
    size_t base = ((size_t)t * NW_ + n0 + n) * 64 + kseg;
    #pragma unroll
    for (int i = 0; i < 4; ++i)
        *reinterpret_cast<f32x4*>(dst + base + i * 4) =
            *reinterpret_cast<f32x4*>(&red[n * 68 + kseg + i * 4]);
}

// Softmax: grid (13, 30), 256 thr. Sums the two logit halves, invnorm+bias, softmax
// over k, writes aT (bf16 a*inv, [t][k][n] coalesced) + asum.
__global__ __launch_bounds__(256) void k_softmax(
    const float* __restrict__ logitsH, const float* __restrict__ logitsL,
    const float* __restrict__ sumsq, const float* __restrict__ b,
    unsigned short* __restrict__ aT, float* __restrict__ asum)
{
    __shared__ unsigned short sT[64 * 66];   // [k][n] pitch 66
    __shared__ float asl[64];
    int nt = blockIdx.x, t = blockIdx.y;
    int n0 = nt * 64;
    int tid = threadIdx.x;
    if (tid < 64) asl[tid] = 0.f;
    __syncthreads();

    int n = tid >> 2, kseg = (tid & 3) * 16;
    int n_g = n0 + n;
    bool valid = n_g < N_;
    size_t base = ((size_t)t * NW_ + n_g) * 64 + kseg;

    float lg[16];
    #pragma unroll
    for (int i = 0; i < 4; ++i) {
        f32x4 h = *reinterpret_cast<const f32x4*>(logitsH + base + i * 4);
        f32x4 l = *reinterpret_cast<const f32x4*>(logitsL + base + i * 4);
        #pragma unroll
        for (int r = 0; r < 4; ++r) lg[i * 4 + r] = h[r] + l[r];
    }
    float s = valid ? sumsq[t * N_ + n_g] : 0.f;
    float inv = 1.0f / fmaxf(sqrtf(s), EPSV);
    float mx = -1e30f;
    #pragma unroll
    for (int u = 0; u < 16; ++u) {
        lg[u] = fmaf(lg[u], inv, b[kseg + u]);
        mx = fmaxf(mx, lg[u]);
    }
    mx = fmaxf(mx, __shfl_xor(mx, 1, 64));
    mx = fmaxf(mx, __shfl_xor(mx, 2, 64));
    float se = 0.f;
    #pragma unroll
    for (int u = 0; u < 16; ++u) { lg[u] = __expf(lg[u] - mx); se += lg[u]; }
    se += __shfl_xor(se, 1, 64);
    se += __shfl_xor(se, 2, 64);
    float rs = 1.0f / se;

    #pragma unroll
    for (int u = 0; u < 16; ++u) {
        float a = valid ? lg[u] * rs : 0.f;
        sT[(kseg + u) * 66 + n] = valid ? f2bf(a * inv) : (unsigned short)0;
        atomicAdd(&asl[kseg + u], a);
    }
    __syncthreads();

    // coalesced aT write: 64 k-rows x 64 n ushort
    #pragma unroll
    for (int i = 0; i < 4; ++i) {
        int idx = tid + i * 256;
        int k = idx >> 4, seg = (idx & 15) * 4;
        ushort4 v4;
        v4.x = sT[k * 66 + seg + 0]; v4.y = sT[k * 66 + seg + 1];
        v4.z = sT[k * 66 + seg + 2]; v4.w = sT[k * 66 + seg + 3];
        *reinterpret_cast<ushort4*>(aT + ((size_t)t * 64 + k) * NA_ + n0 + seg) = v4;
    }
    if (tid < 64) atomicAdd(&asum[t * 64 + tid], asl[tid]);
}

// vlad[t][k][c] = sum_n ahat[k][n]*x[c][n] - asum[k]*cent[k][c]; g2[t][k] = sum_c v^2.
// grid (32, 30), 256 thr. Block: 16 c x 64 k; n split over 4 waves. x re-read is L3-hot.
__global__ __launch_bounds__(256) void k_vlad(
    const float* __restrict__ x, const unsigned short* __restrict__ aT,
    const float* __restrict__ asum, const float* __restrict__ cent,
    float* __restrict__ vlad, float* __restrict__ g2)
{
    __shared__ float red[4][16 * 68];
    int t = blockIdx.y, c0 = blockIdx.x * 16;
    int tid = threadIdx.x;
    int w = tid >> 6, L = tid & 63, lid = L & 15, quad = L >> 4;

    f32x4 acc[4];
    #pragma unroll
    for (int mt = 0; mt < 4; ++mt)
        #pragma unroll
        for (int r = 0; r < 4; ++r) acc[mt][r] = 0.f;

    const float* xrow = x + ((size_t)t * C_ + c0 + lid) * N_;
    const unsigned short* ab = aT + (size_t)t * 64 * NA_;

    for (int s = w; s < 26; s += 4) {
        int nb = s * 32 + quad * 8;
        int nbc = nb > 776 ? 776 : nb;   // clamped lanes multiply aT zeros
        float4 x0 = *reinterpret_cast<const float4*>(xrow + nbc);
        float4 x1 = *reinterpret_cast<const float4*>(xrow + nbc + 4);
        bf16x8 bb;
        bb[0] = (short)f2bf(x0.x); bb[1] = (short)f2bf(x0.y);
        bb[2] = (short)f2bf(x0.z); bb[3] = (short)f2bf(x0.w);
        bb[4] = (short)f2bf(x1.x); bb[5] = (short)f2bf(x1.y);
        bb[6] = (short)f2bf(x1.z); bb[7] = (short)f2bf(x1.w);
        #pragma unroll
        for (int mt = 0; mt < 4; ++mt) {
            bf16x8 af = *reinterpret_cast<const bf16x8*>(ab + (size_t)(mt * 16 + lid) * NA_ + nb);
            acc[mt] = __builtin_amdgcn_mfma_f32_16x16x32_bf16(af, bb, acc[mt], 0, 0, 0);
        }
    }
    {
        float* rp = &red[w][0];
        #pragma unroll
        for (int mt = 0; mt < 4; ++mt)
            *reinterpret_cast<f32x4*>(&rp[lid * 68 + mt * 16 + quad * 4]) = acc[mt];
    }
    __syncthreads();

    int k = tid >> 2, cs4 = (tid & 3) * 4;
    float as = asum[t * 64 + k];
    float4 cv = *reinterpret_cast<const float4*>(cent + k * C_ + c0 + cs4);
    float4 vout;
    float s2 = 0.f;
    #pragma unroll
    for (int j = 0; j < 4; ++j) {
        int cc = cs4 + j;
        float v = red[0][cc * 68 + k] + red[1][cc * 68 + k]
                + red[2][cc * 68 + k] + red[3][cc * 68 + k];
        v -= as * ((const float*)&cv)[j];
        ((float*)&vout)[j] = v;
        s2 = fmaf(v, v, s2);
    }
    *reinterpret_cast<float4*>(vlad + ((size_t)t * 64 + k) * C_ + c0 + cs4) = vout;
    s2 += __shfl_xor(s2, 1, 64);
    s2 += __shfl_xor(s2, 2, 64);
    if ((tid & 3) == 0) atomicAdd(&g2[t * 64 + k], s2);
}

// out[k*512+c] = sum_t vlad * inv_intra * inv_g  (norm factors from g2)
__global__ __launch_bounds__(256) void k_out(
    const float* __restrict__ vlad, const float* __restrict__ g2,
    float* __restrict__ out)
{
    __shared__ float intr[1920];
    __shared__ float sinv[T_];
    int tid = threadIdx.x;
    for (int i = tid; i < 1920; i += 256)
        intr[i] = 1.0f / fmaxf(sqrtf(g2[i]), EPSV);
    __syncthreads();
    if (tid < T_) {
        float s = 0.f;
        #pragma unroll 8
        for (int k = 0; k < 64; ++k) {
            float iv = intr[tid * 64 + k];
            s += g2[tid * 64 + k] * iv * iv;
        }
        sinv[tid] = 1.0f / fmaxf(sqrtf(s), EPSV);
    }
    __syncthreads();
    int idx = blockIdx.x * 256 + tid;  // k*512+c
    int k = idx >> 9;
    float s = 0.f;
    #pragma unroll 5
    for (int t = 0; t < T_; ++t)
        s += vlad[(size_t)t * 32768 + idx] * intr[t * 64 + k] * sinv[t];
    out[idx] = s;
}

extern "C" void kernel_launch(void* const* d_in, const int* in_sizes, int n_in,
                              void* d_out, int out_size, void* d_ws, size_t ws_size,
                              hipStream_t stream) {
    const float* x    = (const float*)d_in[0];   // 30*512*784
    const float* cent = (const float*)d_in[1];   // 64*512
    const float* w    = (const float*)d_in[2];   // 64*512
    const float* b    = (const float*)d_in[3];   // 64
    float* out = (float*)d_out;

    char* p = (char*)d_ws;
    unsigned short* wh = (unsigned short*)p;  p += 65536;
    unsigned short* wl = (unsigned short*)p;  p += 65536;
    // sumsq + asum + g2 contiguous -> one small memset
    float* sumsq = (float*)p;                 p += 30 * 784 * 4;               // 94,080
    float* asum  = (float*)p;                 p += 1920 * 4;
    float* g2    = (float*)p;                 p += 1920 * 4;
    unsigned short* aT = (unsigned short*)p;  p += (size_t)T_ * 64 * NA_ * 2;  // 3,194,880
    float* logitsH = (float*)p;               p += (size_t)T_ * NW_ * 64 * 4;  // 6,389,760
    float* logitsL = (float*)p;               p += (size_t)T_ * NW_ * 64 * 4;  // 6,389,760
    float* vlad = (float*)p;                  p += (size_t)T_ * 64 * C_ * 4;   // 3,932,160
    // total ~= 20 MB

    k_prep<<<128, 256, 0, stream>>>(w, wh, wl);
    hipMemsetAsync(sumsq, 0, (30 * 784 + 2 * 1920) * 4, stream);
    k_logits<<<dim3(13, 2, T_), 256, 0, stream>>>(x, wh, wl, logitsH, logitsL, sumsq);
    k_softmax<<<dim3(13, T_), 256, 0, stream>>>(logitsH, logitsL, sumsq, b, aT, asum);
    k_vlad<<<dim3(32, T_), 256, 0, stream>>>(x, aT, asum, cent, vlad, g2);
    k_out<<<128, 256, 0, stream>>>(vlad, g2, out);
}